// Round 18
// baseline (152.210 us; speedup 1.0000x reference)
//
#include <hip/hip_runtime.h>

#define BATCH 4096
#define NF 128
#define NW 128
#define NO 32
#define MT 128     // batch rows per block
#define LDHB 272   // h row stride in BYTES (16B-aligned)
#define FPB 2      // features per block (halves atomic traffic)

// d_ws (u16 elems): wh fp16 [l,f][v][k] | wo fp16 [f][o][k]  (k contiguous)
#define WH_ELEMS (2 * 128 * 128 * 128)
#define WO_ELEMS (128 * 128 * 32)

typedef _Float16 f16x8 __attribute__((ext_vector_type(8)));
typedef float f32x4 __attribute__((ext_vector_type(4)));

static __device__ __forceinline__ unsigned short f2h(float f) {
    return __builtin_bit_cast(unsigned short, (_Float16)f);  // RNE
}
static __device__ __forceinline__ unsigned long long pack4(float a, float b, float c, float d) {
    return (unsigned long long)f2h(a) | ((unsigned long long)f2h(b) << 16) |
           ((unsigned long long)f2h(c) << 32) | ((unsigned long long)f2h(d) << 48);
}
// XOR bank swizzle: 16B-block granular, bijective within the 256B data row.
// All h_sm writers/readers MUST use this (L0 write, wb write, bfr/out reads).
static __device__ __forceinline__ int hoff(int row, int colb) {
    return row * LDHB + (colb ^ ((row & 7) << 4));
}

__global__ void zero_out_kernel(float* __restrict__ out, int n) {
    int i = blockIdx.x * blockDim.x + threadIdx.x;
    if (i < n) out[i] = 0.0f;
}

// Coalesced transpose + fp16 convert via LDS (stride 138 u16: conflict-free).
__global__ __launch_bounds__(256) void prep_weights2(
    const float* __restrict__ Wh, const float* __restrict__ Wo,
    unsigned short* __restrict__ ws) {
    __shared__ unsigned short t_sm[128 * 138];
    unsigned short* wh = ws;
    unsigned short* wo = ws + WH_ELEMS;
    const int b = blockIdx.x;
    const int tid = threadIdx.x;
    if (b < 256) {
        const float* src = Wh + (size_t)b * 16384;  // [k][v]
        for (int i = tid; i < 16384; i += 256) {
            int k = i >> 7, v = i & 127;
            t_sm[v * 138 + k] = f2h(src[i]);  // coalesced read
        }
        __syncthreads();
        unsigned short* dst = wh + (size_t)b * 16384;  // [v][k]
        for (int i = tid; i < 8192; i += 256) {
            int v = i >> 6, kp = i & 63;
            unsigned lo = t_sm[v * 138 + 2 * kp];
            unsigned hi = t_sm[v * 138 + 2 * kp + 1];
            *(unsigned*)&dst[v * 128 + 2 * kp] = lo | (hi << 16);  // coalesced write
        }
    } else {
        const int f = b - 256;
        const float* src = Wo + (size_t)f * 4096;  // [k][o]
        for (int i = tid; i < 4096; i += 256) {
            int k = i >> 5, o = i & 31;
            t_sm[o * 138 + k] = f2h(src[i]);
        }
        __syncthreads();
        unsigned short* dst = wo + (size_t)f * 4096;  // [o][k]
        for (int i = tid; i < 2048; i += 256) {
            int o = i >> 6, kp = i & 63;
            unsigned lo = t_sm[o * 138 + 2 * kp];
            unsigned hi = t_sm[o * 138 + 2 * kp + 1];
            *(unsigned*)&dst[o * 128 + 2 * kp] = lo | (hi << 16);
        }
    }
}

// r15 champion structure (1D v-split, 64-MFMA phases, acc[2][8]+A[2][2],
// no spill) + (1) XOR bank-swizzle on h_sm (r15-r17 conflicts ~13% of cycles,
// write-side dominated) + (2) FPB=2 (halves atomics; peak regs ~115 < 128).
__global__ __launch_bounds__(256, 4) void ngam_fused(
    const float* __restrict__ x, const float* __restrict__ W1,
    const float* __restrict__ b1, const float* __restrict__ bh,
    const float* __restrict__ bo, const unsigned short* __restrict__ ws,
    float* __restrict__ out) {
    __shared__ __align__(16) unsigned char h_sm[MT * LDHB];
    const unsigned short* wh = ws;
    const unsigned short* wo = ws + WH_ELEMS;

    const int fpair = blockIdx.x >> 5;       // 0..63
    const int m0    = (blockIdx.x & 31) * MT;
    const int tid   = threadIdx.x;
    const int wave  = tid >> 6;              // 0..3: owns 32 v-rows (hidden)
    const int lane  = tid & 63;
    const int arow  = lane & 15;             // A row (v/o) / B col (m) / C col
    const int kgrp  = lane >> 4;             // k-group; C row-quad
    const int r0    = wave * 32;             // wave's private rows (output stage)

    f32x4 oacc[2][2];  // over-features accumulator [mt2][ntl] (16 regs)
#pragma unroll
    for (int a = 0; a < 2; ++a)
#pragma unroll
        for (int b = 0; b < 2; ++b) oacc[a][b] = (f32x4){0.f, 0.f, 0.f, 0.f};

    for (int fp = 0; fp < FPB; ++fp) {
        const int f = fpair + fp * (NF / FPB);

        // ---- layer 0: h = relu(x*W1+b1), fp32 exact -> fp16 LDS [m][w] ----
        {
            int m = tid >> 1, c = tid & 1;
            float xv = x[(size_t)(m0 + m) * NF + f];
            const float* w1r = &W1[f * NW];
            const float* b1r = &b1[f * NW];
            for (int jh = 0; jh < 2; ++jh) {  // split unroll: lower reg transient
#pragma unroll
                for (int j = 0; j < 8; ++j) {
                    int wq = c * 64 + (jh * 8 + j) * 4;   // float index
                    float4 w1 = *(const float4*)&w1r[wq];
                    float4 bb = *(const float4*)&b1r[wq];
                    float v0 = fmaxf(xv * w1.x + bb.x, 0.0f);
                    float v1 = fmaxf(xv * w1.y + bb.y, 0.0f);
                    float v2 = fmaxf(xv * w1.z + bb.z, 0.0f);
                    float v3 = fmaxf(xv * w1.w + bb.w, 0.0f);
                    *(unsigned long long*)(h_sm + hoff(m, 2 * wq)) = pack4(v0, v1, v2, v3);
                }
            }
        }
        __syncthreads();

        // ---- two hidden layers (swapped: C[v][m] = Wt . h^T) ----
#pragma unroll
        for (int l = 0; l < 2; ++l) {
            const unsigned short* wp = wh + (size_t)(l * NF + f) * 16384;
            const float* bhl = bh + (size_t)(l * NF + f) * NW;

            f32x4 acc[2][8];  // [vt][mt] = 64 regs; init = bias (4 consecutive v)
#pragma unroll
            for (int vt = 0; vt < 2; ++vt) {
                float4 bb4 = *(const float4*)&bhl[wave * 32 + vt * 16 + kgrp * 4];
#pragma unroll
                for (int mt = 0; mt < 8; ++mt)
                    acc[vt][mt] = (f32x4){bb4.x, bb4.y, bb4.z, bb4.w};
            }
#pragma unroll
            for (int kh = 0; kh < 2; ++kh) {  // A k-half residency: 16 regs
                f16x8 A[2][2];  // [vt][kt2]
#pragma unroll
                for (int vt = 0; vt < 2; ++vt)
#pragma unroll
                    for (int kt2 = 0; kt2 < 2; ++kt2)
                        A[vt][kt2] = *(const f16x8*)&wp[(wave * 32 + vt * 16 + arow) * 128 +
                                                        (kh * 2 + kt2) * 32 + kgrp * 8];
#pragma unroll
                for (int mt = 0; mt < 8; ++mt) {
#pragma unroll
                    for (int kt2 = 0; kt2 < 2; ++kt2) {
                        f16x8 bfr = *(const f16x8*)(h_sm + hoff(mt * 16 + arow,
                                                    64 * (kh * 2 + kt2) + 16 * kgrp));
                        acc[0][mt] = __builtin_amdgcn_mfma_f32_16x16x32_f16(A[0][kt2], bfr, acc[0][mt], 0, 0, 0);
                        acc[1][mt] = __builtin_amdgcn_mfma_f32_16x16x32_f16(A[1][kt2], bfr, acc[1][mt], 0, 0, 0);
                    }
                }
            }
            __syncthreads();  // all waves done reading h
            // ReLU + b64 packed writeback: v = wave*32+vt*16+kgrp*4+[0..3], m = mt*16+arow
#pragma unroll
            for (int vt = 0; vt < 2; ++vt)
#pragma unroll
                for (int mt = 0; mt < 8; ++mt) {
                    f32x4 v = acc[vt][mt];
                    *(unsigned long long*)(h_sm + hoff(mt * 16 + arow,
                                           64 * wave + 32 * vt + 8 * kgrp)) =
                        pack4(fmaxf(v[0], 0.f), fmaxf(v[1], 0.f), fmaxf(v[2], 0.f), fmaxf(v[3], 0.f));
                }
            __syncthreads();  // writeback visible
        }

        // ---- output layer (UNSWAPPED: wave's 32 rows, all 32 cols) ----
        {
            const unsigned short* wop = wo + (size_t)f * 4096;
            const float* bof = bo + (size_t)f * NO;
            f16x8 Bo[2][4];
#pragma unroll
            for (int ntl = 0; ntl < 2; ++ntl)
#pragma unroll
                for (int kt = 0; kt < 4; ++kt)
                    Bo[ntl][kt] = *(const f16x8*)&wop[(ntl * 16 + arow) * 128 + kt * 32 + kgrp * 8];
            f32x4 acc2[2][2];
#pragma unroll
            for (int ntl = 0; ntl < 2; ++ntl) {
                float bv = bof[ntl * 16 + arow];
                acc2[0][ntl] = (f32x4){bv, bv, bv, bv};
                acc2[1][ntl] = acc2[0][ntl];
            }
#pragma unroll
            for (int mt2 = 0; mt2 < 2; ++mt2) {
#pragma unroll
                for (int kt = 0; kt < 4; ++kt) {
                    f16x8 a = *(const f16x8*)(h_sm + hoff(r0 + mt2 * 16 + arow,
                                              64 * kt + 16 * kgrp));
                    acc2[mt2][0] = __builtin_amdgcn_mfma_f32_16x16x32_f16(a, Bo[0][kt], acc2[mt2][0], 0, 0, 0);
                    acc2[mt2][1] = __builtin_amdgcn_mfma_f32_16x16x32_f16(a, Bo[1][kt], acc2[mt2][1], 0, 0, 0);
                }
            }
#pragma unroll
            for (int mt2 = 0; mt2 < 2; ++mt2)
#pragma unroll
                for (int ntl = 0; ntl < 2; ++ntl) oacc[mt2][ntl] += acc2[mt2][ntl];
        }
        __syncthreads();  // h_sm reads done before next feature's layer-0 fill
    }

    // ---- merged atomics (16 lanes -> 16 consecutive dwords of one row) ----
#pragma unroll
    for (int mt2 = 0; mt2 < 2; ++mt2)
#pragma unroll
        for (int ntl = 0; ntl < 2; ++ntl)
#pragma unroll
            for (int r = 0; r < 4; ++r) {
                int row = m0 + r0 + mt2 * 16 + kgrp * 4 + r;
                int col = ntl * 16 + arow;
                atomicAdd(&out[(size_t)row * NO + col], oacc[mt2][ntl][r]);
            }
}

extern "C" void kernel_launch(void* const* d_in, const int* in_sizes, int n_in,
                              void* d_out, int out_size, void* d_ws, size_t ws_size,
                              hipStream_t stream) {
    const float* x  = (const float*)d_in[0];
    const float* W1 = (const float*)d_in[1];
    const float* b1 = (const float*)d_in[2];
    const float* Wh = (const float*)d_in[3];
    const float* bh = (const float*)d_in[4];
    const float* Wo = (const float*)d_in[5];
    const float* bo = (const float*)d_in[6];
    float* out = (float*)d_out;
    unsigned short* ws = (unsigned short*)d_ws;

    zero_out_kernel<<<(BATCH * NO + 255) / 256, 256, 0, stream>>>(out, BATCH * NO);
    prep_weights2<<<384, 256, 0, stream>>>(Wh, Wo, ws);
    ngam_fused<<<(NF / FPB) * (BATCH / MT), 256, 0, stream>>>(x, W1, b1, bh, bo, ws, out);
}

// Round 19
// 103.474 us; speedup vs baseline: 1.4710x; 1.4710x over previous
//
#include <hip/hip_runtime.h>

#define BATCH 4096
#define NF 128
#define NW 128
#define NO 32
#define MT 128    // batch rows per block
#define LDH 136   // h stride in u16 (272B rows: 16B-aligned; reads at 2-way floor)

// d_ws (u16 elems): wh fp16 [l,f][v][k] | wo fp16 [f][o][k]  (k contiguous)
#define WH_ELEMS (2 * 128 * 128 * 128)
#define WO_ELEMS (128 * 128 * 32)

typedef _Float16 f16x8 __attribute__((ext_vector_type(8)));
typedef float f32x4 __attribute__((ext_vector_type(4)));

static __device__ __forceinline__ unsigned short f2h(float f) {
    return __builtin_bit_cast(unsigned short, (_Float16)f);  // RNE
}
static __device__ __forceinline__ unsigned long long pack4(float a, float b, float c, float d) {
    return (unsigned long long)f2h(a) | ((unsigned long long)f2h(b) << 16) |
           ((unsigned long long)f2h(c) << 32) | ((unsigned long long)f2h(d) << 48);
}

// Transpose + fp16 convert (blocks 0..383) and zero the output (384..399):
// one dispatch instead of two.
__global__ __launch_bounds__(256) void prep_weights3(
    const float* __restrict__ Wh, const float* __restrict__ Wo,
    unsigned short* __restrict__ ws, float* __restrict__ out) {
    __shared__ unsigned short t_sm[128 * 138];
    unsigned short* wh = ws;
    unsigned short* wo = ws + WH_ELEMS;
    const int b = blockIdx.x;
    const int tid = threadIdx.x;
    if (b < 256) {
        const float* src = Wh + (size_t)b * 16384;  // [k][v]
        for (int i = tid; i < 16384; i += 256) {
            int k = i >> 7, v = i & 127;
            t_sm[v * 138 + k] = f2h(src[i]);  // coalesced read
        }
        __syncthreads();
        unsigned short* dst = wh + (size_t)b * 16384;  // [v][k]
        for (int i = tid; i < 8192; i += 256) {
            int v = i >> 6, kp = i & 63;
            unsigned lo = t_sm[v * 138 + 2 * kp];
            unsigned hi = t_sm[v * 138 + 2 * kp + 1];
            *(unsigned*)&dst[v * 128 + 2 * kp] = lo | (hi << 16);  // coalesced write
        }
    } else if (b < 384) {
        const int f = b - 256;
        const float* src = Wo + (size_t)f * 4096;  // [k][o]
        for (int i = tid; i < 4096; i += 256) {
            int k = i >> 5, o = i & 31;
            t_sm[o * 138 + k] = f2h(src[i]);
        }
        __syncthreads();
        unsigned short* dst = wo + (size_t)f * 4096;  // [o][k]
        for (int i = tid; i < 2048; i += 256) {
            int o = i >> 6, kp = i & 63;
            unsigned lo = t_sm[o * 138 + 2 * kp];
            unsigned hi = t_sm[o * 138 + 2 * kp + 1];
            *(unsigned*)&dst[o * 128 + 2 * kp] = lo | (hi << 16);
        }
    } else {
        // zero out[4096*32] : 16 blocks x 256 threads x 32 floats (float4 stores)
        const int zb = b - 384;
        float4 z = (float4){0.f, 0.f, 0.f, 0.f};
        for (int i = zb * 256 + tid; i < BATCH * NO / 4; i += 16 * 256)
            *(float4*)&out[i * 4] = z;
    }
}

// r15 champion structure (1D v-split, 64-MFMA phases) with the A-preload
// hoisted to the FULL layer: A[2][4]=32 regs, 16 independent b128 loads in
// one batch (one L2 round-trip/layer vs r15's two). Ledger: acc(64)+A(32)
// +temps ~= 114 < 128 cap of (256,4) - this is r14 minus the oacc/FPB
// that made r14 spill. r18 lesson: NO swizzle (reads already at 2-way
// floor; b64-write "conflicts" are the 4-cycle floor, not fixable).
__global__ __launch_bounds__(256, 4) void ngam_fused(
    const float* __restrict__ x, const float* __restrict__ W1,
    const float* __restrict__ b1, const float* __restrict__ bh,
    const float* __restrict__ bo, const unsigned short* __restrict__ ws,
    float* __restrict__ out) {
    __shared__ __align__(16) unsigned short h_sm[MT * LDH];
    const unsigned short* wh = ws;
    const unsigned short* wo = ws + WH_ELEMS;

    const int f    = blockIdx.x >> 5;        // feature (32 batch tiles each)
    const int m0   = (blockIdx.x & 31) * MT;
    const int tid  = threadIdx.x;
    const int wave = tid >> 6;               // 0..3: owns 32 v-rows (hidden)
    const int lane = tid & 63;
    const int arow = lane & 15;              // A row (v/o) / B col (m) / C col
    const int kgrp = lane >> 4;              // k-group; C row-quad
    const int r0   = wave * 32;              // wave's private rows (output stage)

    // ---- layer 0: h = relu(x*W1+b1), fp32 exact -> fp16 LDS [m][w] ----
    {
        int m = tid >> 1, c = tid & 1;
        float xv = x[(size_t)(m0 + m) * NF + f];
        const float* w1r = &W1[f * NW];
        const float* b1r = &b1[f * NW];
        for (int jh = 0; jh < 2; ++jh) {  // split unroll: lower reg transient
#pragma unroll
            for (int j = 0; j < 8; ++j) {
                int wq = c * 64 + (jh * 8 + j) * 4;
                float4 w1 = *(const float4*)&w1r[wq];
                float4 bb = *(const float4*)&b1r[wq];
                float v0 = fmaxf(xv * w1.x + bb.x, 0.0f);
                float v1 = fmaxf(xv * w1.y + bb.y, 0.0f);
                float v2 = fmaxf(xv * w1.z + bb.z, 0.0f);
                float v3 = fmaxf(xv * w1.w + bb.w, 0.0f);
                *(unsigned long long*)&h_sm[m * LDH + wq] = pack4(v0, v1, v2, v3);
            }
        }
    }
    __syncthreads();

    // ---- two hidden layers (swapped: C[v][m] = Wt . h^T) ----
#pragma unroll
    for (int l = 0; l < 2; ++l) {
        const unsigned short* wp = wh + (size_t)(l * NF + f) * 16384;
        const float* bhl = bh + (size_t)(l * NF + f) * NW;

        f16x8 A[2][4];  // wave's 32 v-rows, whole layer: 16 independent b128
#pragma unroll
        for (int vt = 0; vt < 2; ++vt)
#pragma unroll
            for (int kt = 0; kt < 4; ++kt)
                A[vt][kt] = *(const f16x8*)&wp[(wave * 32 + vt * 16 + arow) * 128 +
                                               kt * 32 + kgrp * 8];

        f32x4 acc[2][8];  // [vt][mt] = 64 regs; init = bias (4 consecutive v)
#pragma unroll
        for (int vt = 0; vt < 2; ++vt) {
            float4 bb4 = *(const float4*)&bhl[wave * 32 + vt * 16 + kgrp * 4];
#pragma unroll
            for (int mt = 0; mt < 8; ++mt)
                acc[vt][mt] = (f32x4){bb4.x, bb4.y, bb4.z, bb4.w};
        }
#pragma unroll
        for (int mt = 0; mt < 8; ++mt) {
#pragma unroll
            for (int kt = 0; kt < 4; ++kt) {
                f16x8 bfr = *(const f16x8*)&h_sm[(mt * 16 + arow) * LDH +
                                                 kt * 32 + kgrp * 8];
                acc[0][mt] = __builtin_amdgcn_mfma_f32_16x16x32_f16(A[0][kt], bfr, acc[0][mt], 0, 0, 0);
                acc[1][mt] = __builtin_amdgcn_mfma_f32_16x16x32_f16(A[1][kt], bfr, acc[1][mt], 0, 0, 0);
            }
        }
        __syncthreads();  // all waves done reading h
        // ReLU + b64 packed writeback: v = wave*32+vt*16+kgrp*4+[0..3], m = mt*16+arow
#pragma unroll
        for (int vt = 0; vt < 2; ++vt)
#pragma unroll
            for (int mt = 0; mt < 8; ++mt) {
                f32x4 v = acc[vt][mt];
                *(unsigned long long*)&h_sm[(mt * 16 + arow) * LDH + wave * 32 + vt * 16 + kgrp * 4] =
                    pack4(fmaxf(v[0], 0.f), fmaxf(v[1], 0.f), fmaxf(v[2], 0.f), fmaxf(v[3], 0.f));
            }
        __syncthreads();  // writeback visible
    }

    // ---- output layer (UNSWAPPED: wave's 32 rows, all 32 cols) + atomics ----
    {
        const unsigned short* wop = wo + (size_t)f * 4096;
        const float* bof = bo + (size_t)f * NO;
        f16x8 Bo[2][4];
#pragma unroll
        for (int ntl = 0; ntl < 2; ++ntl)
#pragma unroll
            for (int kt = 0; kt < 4; ++kt)
                Bo[ntl][kt] = *(const f16x8*)&wop[(ntl * 16 + arow) * 128 + kt * 32 + kgrp * 8];
        f32x4 acc2[2][2];
#pragma unroll
        for (int ntl = 0; ntl < 2; ++ntl) {
            float bv = bof[ntl * 16 + arow];
            acc2[0][ntl] = (f32x4){bv, bv, bv, bv};
            acc2[1][ntl] = acc2[0][ntl];
        }
#pragma unroll
        for (int mt2 = 0; mt2 < 2; ++mt2) {
#pragma unroll
            for (int kt = 0; kt < 4; ++kt) {
                f16x8 a = *(const f16x8*)&h_sm[(r0 + mt2 * 16 + arow) * LDH + kt * 32 + kgrp * 8];
                acc2[mt2][0] = __builtin_amdgcn_mfma_f32_16x16x32_f16(a, Bo[0][kt], acc2[mt2][0], 0, 0, 0);
                acc2[mt2][1] = __builtin_amdgcn_mfma_f32_16x16x32_f16(a, Bo[1][kt], acc2[mt2][1], 0, 0, 0);
            }
        }
        // merged atomics (16 lanes -> 16 consecutive dwords of one row)
#pragma unroll
        for (int mt2 = 0; mt2 < 2; ++mt2)
#pragma unroll
            for (int ntl = 0; ntl < 2; ++ntl)
#pragma unroll
                for (int r = 0; r < 4; ++r) {
                    int row = m0 + r0 + mt2 * 16 + kgrp * 4 + r;
                    int col = ntl * 16 + arow;
                    atomicAdd(&out[(size_t)row * NO + col], acc2[mt2][ntl][r]);
                }
    }
}

extern "C" void kernel_launch(void* const* d_in, const int* in_sizes, int n_in,
                              void* d_out, int out_size, void* d_ws, size_t ws_size,
                              hipStream_t stream) {
    const float* x  = (const float*)d_in[0];
    const float* W1 = (const float*)d_in[1];
    const float* b1 = (const float*)d_in[2];
    const float* Wh = (const float*)d_in[3];
    const float* bh = (const float*)d_in[4];
    const float* Wo = (const float*)d_in[5];
    const float* bo = (const float*)d_in[6];
    float* out = (float*)d_out;
    unsigned short* ws = (unsigned short*)d_ws;

    prep_weights3<<<400, 256, 0, stream>>>(Wh, Wo, ws, out);
    ngam_fused<<<NF * (BATCH / MT), 256, 0, stream>>>(x, W1, b1, bh, bo, ws, out);
}

// Round 20
// 101.736 us; speedup vs baseline: 1.4961x; 1.0171x over previous
//
#include <hip/hip_runtime.h>

#define BATCH 4096
#define NF 128
#define NW 128
#define NO 32
#define MT 128    // batch rows per block
#define LDH 136   // h stride in u16 (272B rows: 16B-aligned)

// d_ws (u16 elems): wh fp16 [l,f][v][k] | wo fp16 [f][o][k]  (k contiguous)
#define WH_ELEMS (2 * 128 * 128 * 128)
#define WO_ELEMS (128 * 128 * 32)

typedef _Float16 f16x8 __attribute__((ext_vector_type(8)));
typedef float f32x16 __attribute__((ext_vector_type(16)));

static __device__ __forceinline__ unsigned short f2h(float f) {
    return __builtin_bit_cast(unsigned short, (_Float16)f);  // RNE
}
static __device__ __forceinline__ unsigned long long pack4(float a, float b, float c, float d) {
    return (unsigned long long)f2h(a) | ((unsigned long long)f2h(b) << 16) |
           ((unsigned long long)f2h(c) << 32) | ((unsigned long long)f2h(d) << 48);
}

// Transpose + fp16 convert (blocks 0..383) and zero the output (384..399).
__global__ __launch_bounds__(256) void prep_weights3(
    const float* __restrict__ Wh, const float* __restrict__ Wo,
    unsigned short* __restrict__ ws, float* __restrict__ out) {
    __shared__ unsigned short t_sm[128 * 138];
    unsigned short* wh = ws;
    unsigned short* wo = ws + WH_ELEMS;
    const int b = blockIdx.x;
    const int tid = threadIdx.x;
    if (b < 256) {
        const float* src = Wh + (size_t)b * 16384;  // [k][v]
        for (int i = tid; i < 16384; i += 256) {
            int k = i >> 7, v = i & 127;
            t_sm[v * 138 + k] = f2h(src[i]);  // coalesced read
        }
        __syncthreads();
        unsigned short* dst = wh + (size_t)b * 16384;  // [v][k]
        for (int i = tid; i < 8192; i += 256) {
            int v = i >> 6, kp = i & 63;
            unsigned lo = t_sm[v * 138 + 2 * kp];
            unsigned hi = t_sm[v * 138 + 2 * kp + 1];
            *(unsigned*)&dst[v * 128 + 2 * kp] = lo | (hi << 16);  // coalesced write
        }
    } else if (b < 384) {
        const int f = b - 256;
        const float* src = Wo + (size_t)f * 4096;  // [k][o]
        for (int i = tid; i < 4096; i += 256) {
            int k = i >> 5, o = i & 31;
            t_sm[o * 138 + k] = f2h(src[i]);
        }
        __syncthreads();
        unsigned short* dst = wo + (size_t)f * 4096;  // [o][k]
        for (int i = tid; i < 2048; i += 256) {
            int o = i >> 6, kp = i & 63;
            unsigned lo = t_sm[o * 138 + 2 * kp];
            unsigned hi = t_sm[o * 138 + 2 * kp + 1];
            *(unsigned*)&dst[o * 128 + 2 * kp] = lo | (hi << 16);
        }
    } else {
        const int zb = b - 384;
        float4 z = (float4){0.f, 0.f, 0.f, 0.f};
        for (int i = zb * 256 + tid; i < BATCH * NO / 4; i += 16 * 256)
            *(float4*)&out[i * 4] = z;
    }
}

// r19 structure converted to 32x32x16 MFMA: halves MFMA instruction count
// (72 vs 144/wave) at better FLOP/cy (m119: 8.07 vs 4.85cy), halves A-loads
// (8 b128/layer). Fragment maps (guide, m74/m101-verified): C col=lane&31,
// row=(reg&3)+8(reg>>2)+4(lane>>5); A/B lane holds 8 k-contig f16 at
// kbase=8*(lane>>5) -> both operands stay single b128 reads. Ledger:
// acc 4x16=64 + A 32 ~= 110 < 128 cap of (256,4).
__global__ __launch_bounds__(256, 4) void ngam_fused(
    const float* __restrict__ x, const float* __restrict__ W1,
    const float* __restrict__ b1, const float* __restrict__ bh,
    const float* __restrict__ bo, const unsigned short* __restrict__ ws,
    float* __restrict__ out) {
    __shared__ __align__(16) unsigned short h_sm[MT * LDH];
    const unsigned short* wh = ws;
    const unsigned short* wo = ws + WH_ELEMS;

    const int f     = blockIdx.x >> 5;        // feature (32 batch tiles each)
    const int m0    = (blockIdx.x & 31) * MT;
    const int tid   = threadIdx.x;
    const int wave  = tid >> 6;               // 0..3: owns 32 v-rows (hidden)
    const int lane  = tid & 63;
    const int l31   = lane & 31;              // A row (v) / B col (m/o) / C col
    const int khalf = lane >> 5;              // k-half: kbase = 8*khalf

    // ---- layer 0: h = relu(x*W1+b1), fp32 exact -> fp16 LDS [m][w] ----
    {
        int m = tid >> 1, c = tid & 1;
        float xv = x[(size_t)(m0 + m) * NF + f];
        const float* w1r = &W1[f * NW];
        const float* b1r = &b1[f * NW];
        for (int jh = 0; jh < 2; ++jh) {  // split unroll: lower reg transient
#pragma unroll
            for (int j = 0; j < 8; ++j) {
                int wq = c * 64 + (jh * 8 + j) * 4;
                float4 w1 = *(const float4*)&w1r[wq];
                float4 bb = *(const float4*)&b1r[wq];
                float v0 = fmaxf(xv * w1.x + bb.x, 0.0f);
                float v1 = fmaxf(xv * w1.y + bb.y, 0.0f);
                float v2 = fmaxf(xv * w1.z + bb.z, 0.0f);
                float v3 = fmaxf(xv * w1.w + bb.w, 0.0f);
                *(unsigned long long*)&h_sm[m * LDH + wq] = pack4(v0, v1, v2, v3);
            }
        }
    }
    __syncthreads();

    // ---- two hidden layers (swapped: C[v][m] = Wt . h^T, 32x32 tiles) ----
#pragma unroll
    for (int l = 0; l < 2; ++l) {
        const unsigned short* wp = wh + (size_t)(l * NF + f) * 16384;
        const float* bhl = bh + (size_t)(l * NF + f) * NW;

        f16x8 A[8];  // wave's 32v x 128k A panel: 8 b128 (32 regs)
#pragma unroll
        for (int ks = 0; ks < 8; ++ks)
            A[ks] = *(const f16x8*)&wp[(wave * 32 + l31) * 128 + ks * 16 + khalf * 8];

        // bias init: reg r -> v = wave*32 + (r&3) + 8*(r>>2) + 4*khalf
        f32x16 binit;
#pragma unroll
        for (int q = 0; q < 4; ++q) {
            float4 bb4 = *(const float4*)&bhl[wave * 32 + 8 * q + 4 * khalf];
            binit[4 * q + 0] = bb4.x; binit[4 * q + 1] = bb4.y;
            binit[4 * q + 2] = bb4.z; binit[4 * q + 3] = bb4.w;
        }
        f32x16 acc[4];  // [mt] = 64 regs
#pragma unroll
        for (int mt = 0; mt < 4; ++mt) acc[mt] = binit;

#pragma unroll
        for (int mt = 0; mt < 4; ++mt) {
#pragma unroll
            for (int ks = 0; ks < 8; ++ks) {
                f16x8 bfr = *(const f16x8*)&h_sm[(mt * 32 + l31) * LDH + ks * 16 + khalf * 8];
                acc[mt] = __builtin_amdgcn_mfma_f32_32x32x16_f16(A[ks], bfr, acc[mt], 0, 0, 0);
            }
        }
        __syncthreads();  // all waves done reading h
        // ReLU + b64 packed writeback: m = mt*32+l31, v = wave*32+8q+4*khalf+[0..3]
#pragma unroll
        for (int mt = 0; mt < 4; ++mt)
#pragma unroll
            for (int q = 0; q < 4; ++q)
                *(unsigned long long*)&h_sm[(mt * 32 + l31) * LDH + wave * 32 + 8 * q + 4 * khalf] =
                    pack4(fmaxf(acc[mt][4 * q + 0], 0.f), fmaxf(acc[mt][4 * q + 1], 0.f),
                          fmaxf(acc[mt][4 * q + 2], 0.f), fmaxf(acc[mt][4 * q + 3], 0.f));
        __syncthreads();  // writeback visible
    }

    // ---- output layer (UNSWAPPED: C[m][o] = h . Wo, one 32x32 tile) ----
    {
        const unsigned short* wop = wo + (size_t)f * 4096;
        const float* bof = bo + (size_t)f * NO;
        f16x8 Bo[8];  // o-col fragment panel (32 regs)
#pragma unroll
        for (int ks = 0; ks < 8; ++ks)
            Bo[ks] = *(const f16x8*)&wop[l31 * 128 + ks * 16 + khalf * 8];
        float bv = bof[l31];  // C col = o = l31 for all regs
        f32x16 acc2;
#pragma unroll
        for (int i = 0; i < 16; ++i) acc2[i] = bv;
#pragma unroll
        for (int ks = 0; ks < 8; ++ks) {
            f16x8 a = *(const f16x8*)&h_sm[(wave * 32 + l31) * LDH + ks * 16 + khalf * 8];
            acc2 = __builtin_amdgcn_mfma_f32_32x32x16_f16(a, Bo[ks], acc2, 0, 0, 0);
        }
        // atomics: reg r -> row = m0+wave*32+(r&3)+8(r>>2)+4*khalf, col = l31
        // (32 lanes hit one full 128B line of out -> fully merged)
#pragma unroll
        for (int r = 0; r < 16; ++r) {
            int row = m0 + wave * 32 + (r & 3) + 8 * (r >> 2) + 4 * khalf;
            atomicAdd(&out[(size_t)row * NO + l31], acc2[r]);
        }
    }
}

extern "C" void kernel_launch(void* const* d_in, const int* in_sizes, int n_in,
                              void* d_out, int out_size, void* d_ws, size_t ws_size,
                              hipStream_t stream) {
    const float* x  = (const float*)d_in[0];
    const float* W1 = (const float*)d_in[1];
    const float* b1 = (const float*)d_in[2];
    const float* Wh = (const float*)d_in[3];
    const float* bh = (const float*)d_in[4];
    const float* Wo = (const float*)d_in[5];
    const float* bo = (const float*)d_in[6];
    float* out = (float*)d_out;
    unsigned short* ws = (unsigned short*)d_ws;

    prep_weights3<<<400, 256, 0, stream>>>(Wh, Wo, ws, out);
    ngam_fused<<<NF * (BATCH / MT), 256, 0, stream>>>(x, W1, b1, bh, bo, ws, out);
}

// Round 21
// 101.519 us; speedup vs baseline: 1.4993x; 1.0021x over previous
//
#include <hip/hip_runtime.h>

#define BATCH 4096
#define NF 128
#define NW 128
#define NO 32
#define MT 128    // batch rows per block
#define LDH 136   // h stride in u16 (272B rows: 16B-aligned)

// d_ws (u16 elems): wh fp16 [l,f][v][k] | wo fp16 [f][o][k] | xT fp32 [f][m]
#define WH_ELEMS (2 * 128 * 128 * 128)
#define WO_ELEMS (128 * 128 * 32)
#define XT_OFF   (2 * WH_ELEMS / 2 + 0)  // placeholder (computed below)

typedef _Float16 f16x8 __attribute__((ext_vector_type(8)));
typedef _Float16 f16x2 __attribute__((ext_vector_type(2)));
typedef float f32x16 __attribute__((ext_vector_type(16)));

static __device__ __forceinline__ unsigned short f2h(float f) {
    return __builtin_bit_cast(unsigned short, (_Float16)f);  // RNE (prep only)
}
// 2x v_cvt_pkrtz_f16_f32: 2 VALU per 4 values (vs ~7 for cvt+shift/or)
static __device__ __forceinline__ unsigned long long pack4rtz(float a, float b, float c, float d) {
    unsigned lo = __builtin_bit_cast(unsigned, __builtin_amdgcn_cvt_pkrtz(a, b));
    unsigned hi = __builtin_bit_cast(unsigned, __builtin_amdgcn_cvt_pkrtz(c, d));
    return (unsigned long long)lo | ((unsigned long long)hi << 32);
}

// Transpose+fp16 weights (0..383), zero out (384..399), transpose x (400..431).
__global__ __launch_bounds__(256) void prep_weights4(
    const float* __restrict__ Wh, const float* __restrict__ Wo,
    const float* __restrict__ x, unsigned short* __restrict__ ws,
    float* __restrict__ out) {
    __shared__ __align__(16) unsigned char sm_raw[128 * 129 * 4];  // 66KB, shared by all paths
    unsigned short* t_sm = (unsigned short*)sm_raw;
    float* ts = (float*)sm_raw;
    unsigned short* wh = ws;
    unsigned short* wo = ws + WH_ELEMS;
    float* xT = (float*)(ws + WH_ELEMS + WO_ELEMS);
    const int b = blockIdx.x;
    const int tid = threadIdx.x;
    if (b < 256) {
        const float* src = Wh + (size_t)b * 16384;  // [k][v]
        for (int i = tid; i < 16384; i += 256) {
            int k = i >> 7, v = i & 127;
            t_sm[v * 138 + k] = f2h(src[i]);  // coalesced read
        }
        __syncthreads();
        unsigned short* dst = wh + (size_t)b * 16384;  // [v][k]
        for (int i = tid; i < 8192; i += 256) {
            int v = i >> 6, kp = i & 63;
            unsigned lo = t_sm[v * 138 + 2 * kp];
            unsigned hi = t_sm[v * 138 + 2 * kp + 1];
            *(unsigned*)&dst[v * 128 + 2 * kp] = lo | (hi << 16);  // coalesced write
        }
    } else if (b < 384) {
        const int f = b - 256;
        const float* src = Wo + (size_t)f * 4096;  // [k][o]
        for (int i = tid; i < 4096; i += 256) {
            int k = i >> 5, o = i & 31;
            t_sm[o * 138 + k] = f2h(src[i]);
        }
        __syncthreads();
        unsigned short* dst = wo + (size_t)f * 4096;  // [o][k]
        for (int i = tid; i < 2048; i += 256) {
            int o = i >> 6, kp = i & 63;
            unsigned lo = t_sm[o * 138 + 2 * kp];
            unsigned hi = t_sm[o * 138 + 2 * kp + 1];
            *(unsigned*)&dst[o * 128 + 2 * kp] = lo | (hi << 16);
        }
    } else if (b < 400) {
        const int zb = b - 384;
        float4 z = (float4){0.f, 0.f, 0.f, 0.f};
        for (int i = zb * 256 + tid; i < BATCH * NO / 4; i += 16 * 256)
            *(float4*)&out[i * 4] = z;
    } else {
        // transpose x[4096][128] -> xT[128][4096], 128-row slab per block
        const int mb = (b - 400) * 128;
        for (int i = tid; i < 128 * 128; i += 256) {
            int r = i >> 7, f = i & 127;  // consecutive i -> consecutive f: coalesced
            ts[f * 129 + r] = x[(size_t)(mb + r) * NF + f];
        }
        __syncthreads();
        for (int i = tid; i < 128 * 128; i += 256) {
            int f = i >> 7, r = i & 127;  // consecutive i -> consecutive r: coalesced
            xT[(size_t)f * BATCH + mb + r] = ts[f * 129 + r];
        }
    }
}

// r20 structure (32x32x16 MFMA, swapped hidden, unswapped output, merged
// atomics) + pack4rtz (cvt_pkrtz: VALU cut) + coalesced L0 via xT.
// Register ledger: 60 arch-VGPR + 64 AGPR(acc) = 124 < 128 - unchanged.
__global__ __launch_bounds__(256, 4) void ngam_fused(
    const float* __restrict__ W1, const float* __restrict__ b1,
    const float* __restrict__ bh, const float* __restrict__ bo,
    const unsigned short* __restrict__ ws, float* __restrict__ out) {
    __shared__ __align__(16) unsigned short h_sm[MT * LDH];
    const unsigned short* wh = ws;
    const unsigned short* wo = ws + WH_ELEMS;
    const float* xT = (const float*)(ws + WH_ELEMS + WO_ELEMS);

    const int f     = blockIdx.x >> 5;        // feature (32 batch tiles each)
    const int m0    = (blockIdx.x & 31) * MT;
    const int tid   = threadIdx.x;
    const int wave  = tid >> 6;               // 0..3: owns 32 v-rows (hidden)
    const int lane  = tid & 63;
    const int l31   = lane & 31;              // A row (v) / B col (m/o) / C col
    const int khalf = lane >> 5;              // k-half: kbase = 8*khalf

    // ---- layer 0: h = relu(x*W1+b1), fp32 exact -> fp16 LDS [m][w] ----
    {
        int m = tid >> 1, c = tid & 1;
        float xv = xT[(size_t)f * BATCH + m0 + m];  // coalesced
        const float* w1r = &W1[f * NW];
        const float* b1r = &b1[f * NW];
        for (int jh = 0; jh < 2; ++jh) {  // split unroll: lower reg transient
#pragma unroll
            for (int j = 0; j < 8; ++j) {
                int wq = c * 64 + (jh * 8 + j) * 4;
                float4 w1 = *(const float4*)&w1r[wq];
                float4 bb = *(const float4*)&b1r[wq];
                float v0 = fmaxf(xv * w1.x + bb.x, 0.0f);
                float v1 = fmaxf(xv * w1.y + bb.y, 0.0f);
                float v2 = fmaxf(xv * w1.z + bb.z, 0.0f);
                float v3 = fmaxf(xv * w1.w + bb.w, 0.0f);
                *(unsigned long long*)&h_sm[m * LDH + wq] = pack4rtz(v0, v1, v2, v3);
            }
        }
    }
    __syncthreads();

    // ---- two hidden layers (swapped: C[v][m] = Wt . h^T, 32x32 tiles) ----
#pragma unroll
    for (int l = 0; l < 2; ++l) {
        const unsigned short* wp = wh + (size_t)(l * NF + f) * 16384;
        const float* bhl = bh + (size_t)(l * NF + f) * NW;

        f16x8 A[8];  // wave's 32v x 128k A panel: 8 b128 (32 regs)
#pragma unroll
        for (int ks = 0; ks < 8; ++ks)
            A[ks] = *(const f16x8*)&wp[(wave * 32 + l31) * 128 + ks * 16 + khalf * 8];

        // bias init: reg r -> v = wave*32 + (r&3) + 8*(r>>2) + 4*khalf
        f32x16 binit;
#pragma unroll
        for (int q = 0; q < 4; ++q) {
            float4 bb4 = *(const float4*)&bhl[wave * 32 + 8 * q + 4 * khalf];
            binit[4 * q + 0] = bb4.x; binit[4 * q + 1] = bb4.y;
            binit[4 * q + 2] = bb4.z; binit[4 * q + 3] = bb4.w;
        }
        f32x16 acc[4];  // [mt] = 64 regs (AGPR side)
#pragma unroll
        for (int mt = 0; mt < 4; ++mt) acc[mt] = binit;

#pragma unroll
        for (int mt = 0; mt < 4; ++mt) {
#pragma unroll
            for (int ks = 0; ks < 8; ++ks) {
                f16x8 bfr = *(const f16x8*)&h_sm[(mt * 32 + l31) * LDH + ks * 16 + khalf * 8];
                acc[mt] = __builtin_amdgcn_mfma_f32_32x32x16_f16(A[ks], bfr, acc[mt], 0, 0, 0);
            }
        }
        __syncthreads();  // all waves done reading h
        // ReLU + b64 packed writeback: m = mt*32+l31, v = wave*32+8q+4*khalf+[0..3]
#pragma unroll
        for (int mt = 0; mt < 4; ++mt)
#pragma unroll
            for (int q = 0; q < 4; ++q)
                *(unsigned long long*)&h_sm[(mt * 32 + l31) * LDH + wave * 32 + 8 * q + 4 * khalf] =
                    pack4rtz(fmaxf(acc[mt][4 * q + 0], 0.f), fmaxf(acc[mt][4 * q + 1], 0.f),
                             fmaxf(acc[mt][4 * q + 2], 0.f), fmaxf(acc[mt][4 * q + 3], 0.f));
        __syncthreads();  // writeback visible
    }

    // ---- output layer (UNSWAPPED: C[m][o] = h . Wo, one 32x32 tile) ----
    {
        const unsigned short* wop = wo + (size_t)f * 4096;
        const float* bof = bo + (size_t)f * NO;
        f16x8 Bo[8];  // o-col fragment panel (32 regs)
#pragma unroll
        for (int ks = 0; ks < 8; ++ks)
            Bo[ks] = *(const f16x8*)&wop[l31 * 128 + ks * 16 + khalf * 8];
        float bv = bof[l31];  // C col = o = l31 for all regs
        f32x16 acc2;
#pragma unroll
        for (int i = 0; i < 16; ++i) acc2[i] = bv;
#pragma unroll
        for (int ks = 0; ks < 8; ++ks) {
            f16x8 a = *(const f16x8*)&h_sm[(wave * 32 + l31) * LDH + ks * 16 + khalf * 8];
            acc2 = __builtin_amdgcn_mfma_f32_32x32x16_f16(a, Bo[ks], acc2, 0, 0, 0);
        }
        // atomics: reg r -> row = m0+wave*32+(r&3)+8(r>>2)+4*khalf, col = l31
        // (32 lanes hit one full 128B line of out -> fully merged)
#pragma unroll
        for (int r = 0; r < 16; ++r) {
            int row = m0 + wave * 32 + (r & 3) + 8 * (r >> 2) + 4 * khalf;
            atomicAdd(&out[(size_t)row * NO + l31], acc2[r]);
        }
    }
}

extern "C" void kernel_launch(void* const* d_in, const int* in_sizes, int n_in,
                              void* d_out, int out_size, void* d_ws, size_t ws_size,
                              hipStream_t stream) {
    const float* x  = (const float*)d_in[0];
    const float* W1 = (const float*)d_in[1];
    const float* b1 = (const float*)d_in[2];
    const float* Wh = (const float*)d_in[3];
    const float* bh = (const float*)d_in[4];
    const float* Wo = (const float*)d_in[5];
    const float* bo = (const float*)d_in[6];
    float* out = (float*)d_out;
    unsigned short* ws = (unsigned short*)d_ws;

    prep_weights4<<<432, 256, 0, stream>>>(Wh, Wo, x, ws, out);
    ngam_fused<<<NF * (BATCH / MT), 256, 0, stream>>>(W1, b1, bh, bo, ws, out);
}

// Round 22
// 99.987 us; speedup vs baseline: 1.5223x; 1.0153x over previous
//
#include <hip/hip_runtime.h>

#define BATCH 4096
#define NF 128
#define NW 128
#define NO 32
#define MT 128    // batch rows per block
#define LDH 136   // h stride in u16 (272B rows: 16B-aligned)

// d_ws (u16 elems): wh fp16 [l,f][v][k] | wo fp16 [f][o][k] | xT fp32 [f][m]
#define WH_ELEMS (2 * 128 * 128 * 128)
#define WO_ELEMS (128 * 128 * 32)

typedef _Float16 f16x8 __attribute__((ext_vector_type(8)));
typedef float f32x16 __attribute__((ext_vector_type(16)));

static __device__ __forceinline__ unsigned short f2h(float f) {
    return __builtin_bit_cast(unsigned short, (_Float16)f);  // RNE (prep only)
}
// 2x v_cvt_pkrtz_f16_f32: 2 VALU per 4 values
static __device__ __forceinline__ unsigned long long pack4rtz(float a, float b, float c, float d) {
    unsigned lo = __builtin_bit_cast(unsigned, __builtin_amdgcn_cvt_pkrtz(a, b));
    unsigned hi = __builtin_bit_cast(unsigned, __builtin_amdgcn_cvt_pkrtz(c, d));
    return (unsigned long long)lo | ((unsigned long long)hi << 32);
}

// Transpose+fp16 weights (0..383), zero out (384..399), transpose x (400..431).
__global__ __launch_bounds__(256) void prep_weights4(
    const float* __restrict__ Wh, const float* __restrict__ Wo,
    const float* __restrict__ x, unsigned short* __restrict__ ws,
    float* __restrict__ out) {
    __shared__ __align__(16) unsigned char sm_raw[128 * 129 * 4];
    unsigned short* t_sm = (unsigned short*)sm_raw;
    float* ts = (float*)sm_raw;
    unsigned short* wh = ws;
    unsigned short* wo = ws + WH_ELEMS;
    float* xT = (float*)(ws + WH_ELEMS + WO_ELEMS);
    const int b = blockIdx.x;
    const int tid = threadIdx.x;
    if (b < 256) {
        const float* src = Wh + (size_t)b * 16384;  // [k][v]
        for (int i = tid; i < 16384; i += 256) {
            int k = i >> 7, v = i & 127;
            t_sm[v * 138 + k] = f2h(src[i]);  // coalesced read
        }
        __syncthreads();
        unsigned short* dst = wh + (size_t)b * 16384;  // [v][k]
        for (int i = tid; i < 8192; i += 256) {
            int v = i >> 6, kp = i & 63;
            unsigned lo = t_sm[v * 138 + 2 * kp];
            unsigned hi = t_sm[v * 138 + 2 * kp + 1];
            *(unsigned*)&dst[v * 128 + 2 * kp] = lo | (hi << 16);  // coalesced write
        }
    } else if (b < 384) {
        const int f = b - 256;
        const float* src = Wo + (size_t)f * 4096;  // [k][o]
        for (int i = tid; i < 4096; i += 256) {
            int k = i >> 5, o = i & 31;
            t_sm[o * 138 + k] = f2h(src[i]);
        }
        __syncthreads();
        unsigned short* dst = wo + (size_t)f * 4096;  // [o][k]
        for (int i = tid; i < 2048; i += 256) {
            int o = i >> 6, kp = i & 63;
            unsigned lo = t_sm[o * 138 + 2 * kp];
            unsigned hi = t_sm[o * 138 + 2 * kp + 1];
            *(unsigned*)&dst[o * 128 + 2 * kp] = lo | (hi << 16);
        }
    } else if (b < 400) {
        const int zb = b - 384;
        float4 z = (float4){0.f, 0.f, 0.f, 0.f};
        for (int i = zb * 256 + tid; i < BATCH * NO / 4; i += 16 * 256)
            *(float4*)&out[i * 4] = z;
    } else {
        // transpose x[4096][128] -> xT[128][4096], 128-row slab per block
        const int mb = (b - 400) * 128;
        for (int i = tid; i < 128 * 128; i += 256) {
            int r = i >> 7, f = i & 127;
            ts[f * 129 + r] = x[(size_t)(mb + r) * NF + f];
        }
        __syncthreads();
        for (int i = tid; i < 128 * 128; i += 256) {
            int f = i >> 7, r = i & 127;
            xT[(size_t)f * BATCH + mb + r] = ts[f * 129 + r];
        }
    }
}

// r21 structure + (1) XCD-chunked swizzle: same-f blocks land on one XCD's L2
// (weight panels fetched once/XCD; A-load phase hits warm L2) and
// (2) s_setprio(1) around MFMA clusters (blocks are phase-staggered -> MFMA
// waves win arbitration, attn-style T5). Both register-neutral: ledger is
// 60 arch + 64 AGPR = 124/128 with zero headroom.
__global__ __launch_bounds__(256, 4) void ngam_fused(
    const float* __restrict__ W1, const float* __restrict__ b1,
    const float* __restrict__ bh, const float* __restrict__ bo,
    const unsigned short* __restrict__ ws, float* __restrict__ out) {
    __shared__ __align__(16) unsigned short h_sm[MT * LDH];
    const unsigned short* wh = ws;
    const unsigned short* wo = ws + WH_ELEMS;
    const float* xT = (const float*)(ws + WH_ELEMS + WO_ELEMS);

    // XCD-chunked bijective swizzle (4096 = 8 XCDs x 512): XCD k owns
    // logical blocks [k*512, (k+1)*512) = features [k*16, (k+1)*16).
    const int bid   = blockIdx.x;
    const int lb    = (bid & 7) * 512 + (bid >> 3);
    const int f     = lb >> 5;
    const int m0    = (lb & 31) * MT;
    const int tid   = threadIdx.x;
    const int wave  = tid >> 6;
    const int lane  = tid & 63;
    const int l31   = lane & 31;              // A row (v) / B col (m/o) / C col
    const int khalf = lane >> 5;              // k-half: kbase = 8*khalf

    // ---- layer 0: h = relu(x*W1+b1), fp32 exact -> fp16 LDS [m][w] ----
    {
        int m = tid >> 1, c = tid & 1;
        float xv = xT[(size_t)f * BATCH + m0 + m];  // coalesced
        const float* w1r = &W1[f * NW];
        const float* b1r = &b1[f * NW];
        for (int jh = 0; jh < 2; ++jh) {
#pragma unroll
            for (int j = 0; j < 8; ++j) {
                int wq = c * 64 + (jh * 8 + j) * 4;
                float4 w1 = *(const float4*)&w1r[wq];
                float4 bb = *(const float4*)&b1r[wq];
                float v0 = fmaxf(xv * w1.x + bb.x, 0.0f);
                float v1 = fmaxf(xv * w1.y + bb.y, 0.0f);
                float v2 = fmaxf(xv * w1.z + bb.z, 0.0f);
                float v3 = fmaxf(xv * w1.w + bb.w, 0.0f);
                *(unsigned long long*)&h_sm[m * LDH + wq] = pack4rtz(v0, v1, v2, v3);
            }
        }
    }
    __syncthreads();

    // ---- two hidden layers (swapped: C[v][m] = Wt . h^T, 32x32 tiles) ----
#pragma unroll
    for (int l = 0; l < 2; ++l) {
        const unsigned short* wp = wh + (size_t)(l * NF + f) * 16384;
        const float* bhl = bh + (size_t)(l * NF + f) * NW;

        f16x8 A[8];  // wave's 32v x 128k A panel: 8 b128 (32 regs)
#pragma unroll
        for (int ks = 0; ks < 8; ++ks)
            A[ks] = *(const f16x8*)&wp[(wave * 32 + l31) * 128 + ks * 16 + khalf * 8];

        f32x16 binit;
#pragma unroll
        for (int q = 0; q < 4; ++q) {
            float4 bb4 = *(const float4*)&bhl[wave * 32 + 8 * q + 4 * khalf];
            binit[4 * q + 0] = bb4.x; binit[4 * q + 1] = bb4.y;
            binit[4 * q + 2] = bb4.z; binit[4 * q + 3] = bb4.w;
        }
        f32x16 acc[4];  // [mt] = 64 AGPRs
#pragma unroll
        for (int mt = 0; mt < 4; ++mt) acc[mt] = binit;

        __builtin_amdgcn_s_setprio(1);
#pragma unroll
        for (int mt = 0; mt < 4; ++mt) {
#pragma unroll
            for (int ks = 0; ks < 8; ++ks) {
                f16x8 bfr = *(const f16x8*)&h_sm[(mt * 32 + l31) * LDH + ks * 16 + khalf * 8];
                acc[mt] = __builtin_amdgcn_mfma_f32_32x32x16_f16(A[ks], bfr, acc[mt], 0, 0, 0);
            }
        }
        __builtin_amdgcn_s_setprio(0);
        __syncthreads();  // all waves done reading h
        // ReLU + b64 packed writeback: m = mt*32+l31, v = wave*32+8q+4*khalf+[0..3]
#pragma unroll
        for (int mt = 0; mt < 4; ++mt)
#pragma unroll
            for (int q = 0; q < 4; ++q)
                *(unsigned long long*)&h_sm[(mt * 32 + l31) * LDH + wave * 32 + 8 * q + 4 * khalf] =
                    pack4rtz(fmaxf(acc[mt][4 * q + 0], 0.f), fmaxf(acc[mt][4 * q + 1], 0.f),
                             fmaxf(acc[mt][4 * q + 2], 0.f), fmaxf(acc[mt][4 * q + 3], 0.f));
        __syncthreads();  // writeback visible
    }

    // ---- output layer (UNSWAPPED: C[m][o] = h . Wo, one 32x32 tile) ----
    {
        const unsigned short* wop = wo + (size_t)f * 4096;
        const float* bof = bo + (size_t)f * NO;
        f16x8 Bo[8];
#pragma unroll
        for (int ks = 0; ks < 8; ++ks)
            Bo[ks] = *(const f16x8*)&wop[l31 * 128 + ks * 16 + khalf * 8];
        float bv = bof[l31];
        f32x16 acc2;
#pragma unroll
        for (int i = 0; i < 16; ++i) acc2[i] = bv;
        __builtin_amdgcn_s_setprio(1);
#pragma unroll
        for (int ks = 0; ks < 8; ++ks) {
            f16x8 a = *(const f16x8*)&h_sm[(wave * 32 + l31) * LDH + ks * 16 + khalf * 8];
            acc2 = __builtin_amdgcn_mfma_f32_32x32x16_f16(a, Bo[ks], acc2, 0, 0, 0);
        }
        __builtin_amdgcn_s_setprio(0);
        // atomics: reg r -> row = m0+wave*32+(r&3)+8(r>>2)+4*khalf, col = l31
#pragma unroll
        for (int r = 0; r < 16; ++r) {
            int row = m0 + wave * 32 + (r & 3) + 8 * (r >> 2) + 4 * khalf;
            atomicAdd(&out[(size_t)row * NO + l31], acc2[r]);
        }
    }
}

extern "C" void kernel_launch(void* const* d_in, const int* in_sizes, int n_in,
                              void* d_out, int out_size, void* d_ws, size_t ws_size,
                              hipStream_t stream) {
    const float* x  = (const float*)d_in[0];
    const float* W1 = (const float*)d_in[1];
    const float* b1 = (const float*)d_in[2];
    const float* Wh = (const float*)d_in[3];
    const float* bh = (const float*)d_in[4];
    const float* Wo = (const float*)d_in[5];
    const float* bo = (const float*)d_in[6];
    float* out = (float*)d_out;
    unsigned short* ws = (unsigned short*)d_ws;

    prep_weights4<<<432, 256, 0, stream>>>(Wh, Wo, x, ws, out);
    ngam_fused<<<NF * (BATCH / MT), 256, 0, stream>>>(W1, b1, bh, bo, ws, out);
}